// Round 1
// baseline (500.164 us; speedup 1.0000x reference)
//
#include <hip/hip_runtime.h>
#include <math.h>

#define B_      16
#define M_      32
#define A_TOT   21824
#define NROWS   (B_*A_TOT)      // 349184
#define NUM_FG_ 80
#define EPSF    1e-6f
#define NCAND   45
#define NBF     2048            // fused-kernel grid (8 blocks/CU)

typedef float f32x4 __attribute__((ext_vector_type(4)));

__device__ __forceinline__ float waveReduceSum(float v) {
    for (int o = 32; o > 0; o >>= 1) v += __shfl_down(v, o, 64);
    return v;
}

// ---------------- ATSS assignment: one wave per (b, gt) ----------------
// Top-9 nearest per level via analytic 7x7 window (worst-case 9th nearest
// <= 2.13*s, outside-window >= 3.5*s -> no ambiguity; validated absmax==0).
// Extraction by rank-counting in LDS; rank<9 scatters anchor index to
// cand[level*9+rank] -- identical order to the validated wave-min kernel,
// so the threshold tail below is bit-identical.
__global__ __launch_bounds__(64) void k_assign(
    const float* __restrict__ anchors,
    const float* __restrict__ gtb,
    unsigned long long* __restrict__ keys)
{
    const int   lvl_base[5] = {0, 16384, 20480, 21504, 21760};
    const int   lvl_f[5]    = {128, 64, 32, 16, 8};
    const float lvl_s[5]    = {8.f, 16.f, 32.f, 64.f, 128.f};
    int bg = blockIdx.x;
    int b = bg >> 5, g = bg & 31;
    const float* gt = gtb + (b * M_ + g) * 5;
    float g0 = gt[0], g1 = gt[1], g2 = gt[2], g3 = gt[3];
    bool valid = gt[4] > 0.f;
    float gcx = (g0 + g2) * 0.5f, gcy = (g1 + g3) * 0.5f;
    int lane = threadIdx.x;

    __shared__ unsigned long long kbuf[5 * 49];
    __shared__ int cand[NCAND];

    unsigned long long mykey[4];
    int myanchor[4];
    // phase 1: compute 245 candidate keys (centers analytic & exact in fp32)
#pragma unroll
    for (int q = 0; q < 4; ++q) {
        int cid = lane + 64 * q;
        mykey[q] = ~0ULL;
        if (cid < 245) {
            int l = cid / 49, j = cid - l * 49;
            int f = lvl_f[l];
            float s = lvl_s[l];
            int ixn = (int)floorf(gcx / s); ixn = min(max(ixn, 0), f - 1);
            int iyn = (int)floorf(gcy / s); iyn = min(max(iyn, 0), f - 1);
            int ix0 = min(max(ixn - 3, 0), f - 7);
            int iy0 = min(max(iyn - 3, 0), f - 7);
            int ix = ix0 + j % 7, iy = iy0 + j / 7;
            int a = lvl_base[l] + iy * f + ix;   // row=y (ij meshgrid), col=x
            float acx = ((float)ix + 0.5f) * s;  // == (an.x+an.z)*0.5 bit-exact
            float acy = ((float)iy + 0.5f) * s;
            float dx = acx - gcx, dy = acy - gcy;
            float dist = sqrtf(dx * dx + dy * dy);
            mykey[q] = ((unsigned long long)__float_as_uint(dist) << 32) | (unsigned)a;
            myanchor[q] = a;
            kbuf[cid] = mykey[q];
        }
    }
    __syncthreads();
    // phase 2: rank within level; rank<9 -> scatter anchor idx in rank order
#pragma unroll
    for (int q = 0; q < 4; ++q) {
        int cid = lane + 64 * q;
        if (cid < 245) {
            int l = cid / 49;
            const unsigned long long* kg = &kbuf[l * 49];
            int cnt = 0;
            for (int j = 0; j < 49; ++j) cnt += (kg[j] < mykey[q]);
            if (cnt < 9) cand[l * 9 + cnt] = myanchor[q];
        }
    }
    __syncthreads();

    // threshold tail: identical to the validated kernel
    float iou = 0.f; bool inside = false; int a = 0;
    if (lane < NCAND) {
        a = cand[lane];
        float4 an = ((const float4*)anchors)[a];
        float tlx = fmaxf(an.x, g0), tly = fmaxf(an.y, g1);
        float brx = fminf(an.z, g2), bry = fminf(an.w, g3);
        float w = fmaxf(brx - tlx, 0.f), h = fmaxf(bry - tly, 0.f);
        float inter = w * h;
        float aa = (an.z - an.x) * (an.w - an.y);
        float ag = (g2 - g0) * (g3 - g1);
        iou = inter / fmaxf(aa + ag - inter, EPSF);
        float ccx = (an.x + an.z) * 0.5f, ccy = (an.y + an.w) * 0.5f;
        float li = ccx - g0, ti = ccy - g1, ri = g2 - ccx, bi = g3 - ccy;
        inside = fminf(fminf(li, ri), fminf(ti, bi)) > 0.01f;
    }
    float s = waveReduceSum(lane < NCAND ? iou : 0.f);
    float mean = __shfl(s, 0, 64) * (1.f / 45.f);
    float d = (lane < NCAND) ? (iou - mean) : 0.f;
    float ss = waveReduceSum(d * d);
    float thr = mean + sqrtf(__shfl(ss, 0, 64) * (1.f / 44.f));
    if (lane < NCAND && valid && inside && iou >= thr) {
        unsigned long long key =
            ((unsigned long long)__float_as_uint(iou) << 32) | (unsigned)(31 - g);
        atomicMax(&keys[(size_t)b * A_TOT + a], key);
    }
}

// ------- fused: focal cls sweep + fg-row losses + in-kernel final reduce ----
__global__ __launch_bounds__(256) void k_fused(
    const f32x4* __restrict__ cls4,
    const float* __restrict__ pred_reg,
    const float* __restrict__ pred_ctn,
    const float* __restrict__ anchors,
    const float* __restrict__ gtb,
    const unsigned long long* __restrict__ keys,
    double* __restrict__ part,
    unsigned int* __restrict__ cnt,
    float* __restrict__ out)
{
    const int total4 = NROWS * (NUM_FG_ / 4);   // 6,983,680; 80%4==0 -> no row-crossing
    float accC = 0.f, accR = 0.f, accT = 0.f, accJ = 0.f, accF = 0.f;
    for (int i = blockIdx.x * 256 + threadIdx.x; i < total4; i += NBF * 256) {
        f32x4 v = __builtin_nontemporal_load(cls4 + i);   // zero-reuse stream
        int row = i / 20;
        int c0 = (i - row * 20) * 4;
        unsigned long long key = keys[row];
        int tgt = -1;
        int b = row / A_TOT;
        int g = 0;
        if (key) {
            g = 31 - (int)(key & 0xffffffffu);
            tgt = (int)gtb[(b * M_ + g) * 5 + 4] - 1;
        }
        float xs[4] = {v[0], v[1], v[2], v[3]};
#pragma unroll
        for (int j = 0; j < 4; ++j) {
            float x = xs[j];
            float p = 1.f / (1.f + __expf(-x));
            float loss;
            if (c0 + j == tgt)
                loss = -0.25f * (1.f - p) * (1.f - p) * __logf(fmaxf(p, 1e-12f));
            else
                loss = -0.75f * p * p * __logf(fmaxf(1.f - p, 1e-12f));
            accC += loss;
        }
        if (c0 == 0 && key) {   // fg-row losses, once per row (rare: ~0.6% of rows)
            accF += 1.f;
            int aidx = row - b * A_TOT;
            const float* gt = gtb + (b * M_ + g) * 5;
            float g0 = gt[0], g1 = gt[1], g2 = gt[2], g3 = gt[3];
            float4 an = ((const float4*)anchors)[aidx];
            float aw = an.z - an.x, ah = an.w - an.y;
            float ax = (an.x + an.z) * 0.5f, ay = (an.y + an.w) * 0.5f;
            float gw = fmaxf(g2 - g0, EPSF), gh = fmaxf(g3 - g1, EPSF);
            float gx = (g0 + g2) * 0.5f, gy = (g1 + g3) * 0.5f;
            float e0 = (gx - ax) / aw, e1 = (gy - ay) / ah;
            float e2 = __logf(gw / aw), e3 = __logf(gh / ah);
            float tw = __expf(fminf(fmaxf(e2, -4.f), 4.f)) * aw;
            float th = __expf(fminf(fmaxf(e3, -4.f), 4.f)) * ah;
            float tcx = ax + e0 * aw, tcy = ay + e1 * ah;
            float tb0 = tcx - 0.5f * tw, tb1 = tcy - 0.5f * th;
            float tb2 = tcx + 0.5f * tw, tb3 = tcy + 0.5f * th;
            const float* pr = pred_reg + (size_t)row * 8;
            float p0 = pr[0], p1 = pr[1], p2 = pr[2], p3 = pr[3];
            float l0 = pr[4], l1 = pr[5], l2 = pr[6], l3 = pr[7];
            float pw = __expf(fminf(fmaxf(p2, -4.f), 4.f)) * aw;
            float ph = __expf(fminf(fmaxf(p3, -4.f), 4.f)) * ah;
            float pcx = ax + p0 * aw, pcy = ay + p1 * ah;
            float pb0 = pcx - 0.5f * pw, pb1 = pcy - 0.5f * ph;
            float pb2 = pcx + 0.5f * pw, pb3 = pcy + 0.5f * ph;
            float tlx = fmaxf(pb0, tb0), tly = fmaxf(pb1, tb1);
            float brx = fminf(pb2, tb2), bry = fminf(pb3, tb3);
            float iw = fmaxf(brx - tlx, 0.f), ih = fmaxf(bry - tly, 0.f);
            float inter = iw * ih;
            float a1 = (pb2 - pb0) * (pb3 - pb1);
            float a2 = (tb2 - tb0) * (tb3 - tb1);
            float uni = fmaxf(a1 + a2 - inter, EPSF);
            float iou = inter / uni;
            float ex0 = fminf(pb0, tb0), ey0 = fminf(pb1, tb1);
            float ex1 = fmaxf(pb2, tb2), ey1 = fmaxf(pb3, tb3);
            float ew = fmaxf(ex1 - ex0, 0.f), eh = fmaxf(ey1 - ey0, 0.f);
            float enc = fmaxf(ew * eh, EPSF);
            accR += 1.f - (iou - (enc - uni) / enc);
            float cl = fmaxf(ax - tb0, EPSF), cr = fmaxf(tb2 - ax, EPSF);
            float ct = fmaxf(ay - tb1, EPSF), cb = fmaxf(tb3 - ay, EPSF);
            float ratio = fminf(cl, cr) / fmaxf(cl, cr) * (fminf(ct, cb) / fmaxf(ct, cb));
            float cstar = sqrtf(fminf(fmaxf(ratio, EPSF), 1.f));
            float z = pred_ctn[row];
            accT += fmaxf(z, 0.f) - z * cstar + log1pf(__expf(-fabsf(z)));
            float mu[4] = {p0, p1, p2, p3}, ls[4] = {l0, l1, l2, l3};
            float ee[4] = {e0, e1, e2, e3};
            float ksum = 0.f;
#pragma unroll
            for (int k = 0; k < 4; ++k) {
                float var = __expf(2.f * ls[k]);
                float d2 = (mu[k] - ee[k]) * (mu[k] - ee[k]);
                ksum += (-ls[k] + 0.5f * (var + d2) - 0.5f)
                      + ( ls[k] + (1.f + d2) / (2.f * var) - 0.5f);
            }
            accJ += 0.5f * ksum;
        }
    }
    float vC = waveReduceSum(accC), vR = waveReduceSum(accR);
    float vT = waveReduceSum(accT), vJ = waveReduceSum(accJ);
    float vF = waveReduceSum(accF);
    __shared__ float sb[4][5];
    int wid = threadIdx.x >> 6, lid = threadIdx.x & 63;
    if (lid == 0) { sb[wid][0]=vC; sb[wid][1]=vR; sb[wid][2]=vT; sb[wid][3]=vJ; sb[wid][4]=vF; }
    __syncthreads();
    if (threadIdx.x == 0) {
        double C=0,R=0,T=0,J=0,F=0;
        for (int w = 0; w < 4; ++w) { C+=sb[w][0]; R+=sb[w][1]; T+=sb[w][2]; J+=sb[w][3]; F+=sb[w][4]; }
        double* p = part + (size_t)blockIdx.x * 5;
        p[0]=C; p[1]=R; p[2]=T; p[3]=J; p[4]=F;
    }

    // ---- last-block-done final reduction (replaces k_final dispatch) ----
    __shared__ int lastFlag;
    __threadfence();                         // release: publish part slot
    if (threadIdx.x == 0)
        lastFlag = (atomicAdd(cnt, 1u) == (unsigned)(NBF - 1));
    __syncthreads();
    if (!lastFlag) return;
    __threadfence();                         // acquire: see all part slots

    // body identical (same summation order) to the former k_final
    double C = 0, R = 0, T = 0, J = 0, F = 0;
    for (int i = threadIdx.x; i < NBF; i += 256) {
        const double* p = part + (size_t)i * 5;
        C += p[0]; R += p[1]; T += p[2]; J += p[3]; F += p[4];
    }
    for (int o = 32; o > 0; o >>= 1) {
        C += __shfl_down(C, o, 64); R += __shfl_down(R, o, 64);
        T += __shfl_down(T, o, 64); J += __shfl_down(J, o, 64);
        F += __shfl_down(F, o, 64);
    }
    __shared__ double sb2[5][4];
    if (lid == 0) { sb2[0][wid]=C; sb2[1][wid]=R; sb2[2][wid]=T; sb2[3][wid]=J; sb2[4][wid]=F; }
    __syncthreads();
    if (threadIdx.x == 0) {
        double c = sb2[0][0]+sb2[0][1]+sb2[0][2]+sb2[0][3];
        double r = sb2[1][0]+sb2[1][1]+sb2[1][2]+sb2[1][3];
        double t = sb2[2][0]+sb2[2][1]+sb2[2][2]+sb2[2][3];
        double j = sb2[3][0]+sb2[3][1]+sb2[3][2]+sb2[3][3];
        double f = sb2[4][0]+sb2[4][1]+sb2[4][2]+sb2[4][3];
        double ln = 0.9 * 100.0 + 0.1 * fmax(f, 1.0);
        out[0] = (float)(c / ln);
        out[1] = (float)(r / ln);
        out[2] = (float)(t / ln);
        out[3] = (float)(0.1 * j / ln);   // JS_W applied here
    }
}

extern "C" void kernel_launch(void* const* d_in, const int* in_sizes, int n_in,
                              void* d_out, int out_size, void* d_ws, size_t ws_size,
                              hipStream_t stream) {
    (void)in_sizes; (void)n_in; (void)out_size; (void)ws_size;
    const float* pred_cls = (const float*)d_in[0];
    const float* pred_reg = (const float*)d_in[1];
    const float* pred_ctn = (const float*)d_in[2];
    const float* anchors  = (const float*)d_in[3];
    const float* gtb      = (const float*)d_in[4];
    // im_info (d_in[5]) unused

    // ws layout: keys[NROWS] u64 | cnt (8 B, zeroed) | part[NBF*5] doubles
    unsigned long long* keys = (unsigned long long*)d_ws;
    unsigned int* cnt = (unsigned int*)((char*)d_ws + (size_t)NROWS * 8);
    double* part = (double*)((char*)d_ws + (size_t)NROWS * 8 + 8);

    hipMemsetAsync(keys, 0, (size_t)NROWS * 8 + 8, stream);  // keys + counter
    k_assign<<<B_ * M_, 64, 0, stream>>>(anchors, gtb, keys);
    k_fused <<<NBF, 256, 0, stream>>>((const f32x4*)pred_cls, pred_reg, pred_ctn,
                                      anchors, gtb, keys, part, cnt, (float*)d_out);
}

// Round 2
// 388.759 us; speedup vs baseline: 1.2866x; 1.2866x over previous
//
#include <hip/hip_runtime.h>
#include <math.h>

#define B_      16
#define M_      32
#define A_TOT   21824
#define NROWS   (B_*A_TOT)      // 349184
#define NUM_FG_ 80
#define EPSF    1e-6f
#define NCAND   45
#define NBF     2048            // fused-kernel grid (8 blocks/CU)

__device__ __forceinline__ float waveReduceSum(float v) {
    for (int o = 32; o > 0; o >>= 1) v += __shfl_down(v, o, 64);
    return v;
}

// ---------------- ATSS assignment: one wave per (b, gt) ----------------
// Top-9 nearest per level via analytic 7x7 window (worst-case 9th nearest
// <= 2.13*s, outside-window >= 3.5*s -> no ambiguity; validated absmax==0).
// Extraction by rank-counting in LDS; rank<9 scatters anchor index to
// cand[level*9+rank] -- identical order to the validated wave-min kernel,
// so the threshold tail below is bit-identical.
__global__ __launch_bounds__(64) void k_assign(
    const float* __restrict__ anchors,
    const float* __restrict__ gtb,
    unsigned long long* __restrict__ keys)
{
    const int   lvl_base[5] = {0, 16384, 20480, 21504, 21760};
    const int   lvl_f[5]    = {128, 64, 32, 16, 8};
    const float lvl_s[5]    = {8.f, 16.f, 32.f, 64.f, 128.f};
    int bg = blockIdx.x;
    int b = bg >> 5, g = bg & 31;
    const float* gt = gtb + (b * M_ + g) * 5;
    float g0 = gt[0], g1 = gt[1], g2 = gt[2], g3 = gt[3];
    bool valid = gt[4] > 0.f;
    float gcx = (g0 + g2) * 0.5f, gcy = (g1 + g3) * 0.5f;
    int lane = threadIdx.x;

    __shared__ unsigned long long kbuf[5 * 49];
    __shared__ int cand[NCAND];

    unsigned long long mykey[4];
    int myanchor[4];
    // phase 1: compute 245 candidate keys (centers analytic & exact in fp32)
#pragma unroll
    for (int q = 0; q < 4; ++q) {
        int cid = lane + 64 * q;
        mykey[q] = ~0ULL;
        if (cid < 245) {
            int l = cid / 49, j = cid - l * 49;
            int f = lvl_f[l];
            float s = lvl_s[l];
            int ixn = (int)floorf(gcx / s); ixn = min(max(ixn, 0), f - 1);
            int iyn = (int)floorf(gcy / s); iyn = min(max(iyn, 0), f - 1);
            int ix0 = min(max(ixn - 3, 0), f - 7);
            int iy0 = min(max(iyn - 3, 0), f - 7);
            int ix = ix0 + j % 7, iy = iy0 + j / 7;
            int a = lvl_base[l] + iy * f + ix;   // row=y (ij meshgrid), col=x
            float acx = ((float)ix + 0.5f) * s;  // == (an.x+an.z)*0.5 bit-exact
            float acy = ((float)iy + 0.5f) * s;
            float dx = acx - gcx, dy = acy - gcy;
            float dist = sqrtf(dx * dx + dy * dy);
            mykey[q] = ((unsigned long long)__float_as_uint(dist) << 32) | (unsigned)a;
            myanchor[q] = a;
            kbuf[cid] = mykey[q];
        }
    }
    __syncthreads();
    // phase 2: rank within level; rank<9 -> scatter anchor idx in rank order
#pragma unroll
    for (int q = 0; q < 4; ++q) {
        int cid = lane + 64 * q;
        if (cid < 245) {
            int l = cid / 49;
            const unsigned long long* kg = &kbuf[l * 49];
            int cnt = 0;
            for (int j = 0; j < 49; ++j) cnt += (kg[j] < mykey[q]);
            if (cnt < 9) cand[l * 9 + cnt] = myanchor[q];
        }
    }
    __syncthreads();

    // threshold tail: identical to the validated kernel
    float iou = 0.f; bool inside = false; int a = 0;
    if (lane < NCAND) {
        a = cand[lane];
        float4 an = ((const float4*)anchors)[a];
        float tlx = fmaxf(an.x, g0), tly = fmaxf(an.y, g1);
        float brx = fminf(an.z, g2), bry = fminf(an.w, g3);
        float w = fmaxf(brx - tlx, 0.f), h = fmaxf(bry - tly, 0.f);
        float inter = w * h;
        float aa = (an.z - an.x) * (an.w - an.y);
        float ag = (g2 - g0) * (g3 - g1);
        iou = inter / fmaxf(aa + ag - inter, EPSF);
        float ccx = (an.x + an.z) * 0.5f, ccy = (an.y + an.w) * 0.5f;
        float li = ccx - g0, ti = ccy - g1, ri = g2 - ccx, bi = g3 - ccy;
        inside = fminf(fminf(li, ri), fminf(ti, bi)) > 0.01f;
    }
    float s = waveReduceSum(lane < NCAND ? iou : 0.f);
    float mean = __shfl(s, 0, 64) * (1.f / 45.f);
    float d = (lane < NCAND) ? (iou - mean) : 0.f;
    float ss = waveReduceSum(d * d);
    float thr = mean + sqrtf(__shfl(ss, 0, 64) * (1.f / 44.f));
    if (lane < NCAND && valid && inside && iou >= thr) {
        unsigned long long key =
            ((unsigned long long)__float_as_uint(iou) << 32) | (unsigned)(31 - g);
        atomicMax(&keys[(size_t)b * A_TOT + a], key);
    }
}

// ------- fused: focal cls sweep + fg-row losses + in-kernel final reduce ----
__global__ __launch_bounds__(256) void k_fused(
    const float4* __restrict__ cls4,
    const float* __restrict__ pred_reg,
    const float* __restrict__ pred_ctn,
    const float* __restrict__ anchors,
    const float* __restrict__ gtb,
    const unsigned long long* __restrict__ keys,
    double* __restrict__ part,
    unsigned int* __restrict__ cnt,
    float* __restrict__ out)
{
    const int total4 = NROWS * (NUM_FG_ / 4);   // 6,983,680; 80%4==0 -> no row-crossing
    float accC = 0.f, accR = 0.f, accT = 0.f, accJ = 0.f, accF = 0.f;
    for (int i = blockIdx.x * 256 + threadIdx.x; i < total4; i += NBF * 256) {
        float4 v = cls4[i];                     // plain load: L3-resident stream
        int row = i / 20;
        int c0 = (i - row * 20) * 4;
        unsigned long long key = keys[row];
        int tgt = -1;
        int b = row / A_TOT;
        int g = 0;
        if (key) {
            g = 31 - (int)(key & 0xffffffffu);
            tgt = (int)gtb[(b * M_ + g) * 5 + 4] - 1;
        }
        float xs[4] = {v.x, v.y, v.z, v.w};
#pragma unroll
        for (int j = 0; j < 4; ++j) {
            float x = xs[j];
            float p = 1.f / (1.f + __expf(-x));
            float loss;
            if (c0 + j == tgt)
                loss = -0.25f * (1.f - p) * (1.f - p) * __logf(fmaxf(p, 1e-12f));
            else
                loss = -0.75f * p * p * __logf(fmaxf(1.f - p, 1e-12f));
            accC += loss;
        }
        if (c0 == 0 && key) {   // fg-row losses, once per row (rare: ~0.6% of rows)
            accF += 1.f;
            int aidx = row - b * A_TOT;
            const float* gt = gtb + (b * M_ + g) * 5;
            float g0 = gt[0], g1 = gt[1], g2 = gt[2], g3 = gt[3];
            float4 an = ((const float4*)anchors)[aidx];
            float aw = an.z - an.x, ah = an.w - an.y;
            float ax = (an.x + an.z) * 0.5f, ay = (an.y + an.w) * 0.5f;
            float gw = fmaxf(g2 - g0, EPSF), gh = fmaxf(g3 - g1, EPSF);
            float gx = (g0 + g2) * 0.5f, gy = (g1 + g3) * 0.5f;
            float e0 = (gx - ax) / aw, e1 = (gy - ay) / ah;
            float e2 = __logf(gw / aw), e3 = __logf(gh / ah);
            float tw = __expf(fminf(fmaxf(e2, -4.f), 4.f)) * aw;
            float th = __expf(fminf(fmaxf(e3, -4.f), 4.f)) * ah;
            float tcx = ax + e0 * aw, tcy = ay + e1 * ah;
            float tb0 = tcx - 0.5f * tw, tb1 = tcy - 0.5f * th;
            float tb2 = tcx + 0.5f * tw, tb3 = tcy + 0.5f * th;
            const float* pr = pred_reg + (size_t)row * 8;
            float p0 = pr[0], p1 = pr[1], p2 = pr[2], p3 = pr[3];
            float l0 = pr[4], l1 = pr[5], l2 = pr[6], l3 = pr[7];
            float pw = __expf(fminf(fmaxf(p2, -4.f), 4.f)) * aw;
            float ph = __expf(fminf(fmaxf(p3, -4.f), 4.f)) * ah;
            float pcx = ax + p0 * aw, pcy = ay + p1 * ah;
            float pb0 = pcx - 0.5f * pw, pb1 = pcy - 0.5f * ph;
            float pb2 = pcx + 0.5f * pw, pb3 = pcy + 0.5f * ph;
            float tlx = fmaxf(pb0, tb0), tly = fmaxf(pb1, tb1);
            float brx = fminf(pb2, tb2), bry = fminf(pb3, tb3);
            float iw = fmaxf(brx - tlx, 0.f), ih = fmaxf(bry - tly, 0.f);
            float inter = iw * ih;
            float a1 = (pb2 - pb0) * (pb3 - pb1);
            float a2 = (tb2 - tb0) * (tb3 - tb1);
            float uni = fmaxf(a1 + a2 - inter, EPSF);
            float iou = inter / uni;
            float ex0 = fminf(pb0, tb0), ey0 = fminf(pb1, tb1);
            float ex1 = fmaxf(pb2, tb2), ey1 = fmaxf(pb3, tb3);
            float ew = fmaxf(ex1 - ex0, 0.f), eh = fmaxf(ey1 - ey0, 0.f);
            float enc = fmaxf(ew * eh, EPSF);
            accR += 1.f - (iou - (enc - uni) / enc);
            float cl = fmaxf(ax - tb0, EPSF), cr = fmaxf(tb2 - ax, EPSF);
            float ct = fmaxf(ay - tb1, EPSF), cb = fmaxf(tb3 - ay, EPSF);
            float ratio = fminf(cl, cr) / fmaxf(cl, cr) * (fminf(ct, cb) / fmaxf(ct, cb));
            float cstar = sqrtf(fminf(fmaxf(ratio, EPSF), 1.f));
            float z = pred_ctn[row];
            accT += fmaxf(z, 0.f) - z * cstar + log1pf(__expf(-fabsf(z)));
            float mu[4] = {p0, p1, p2, p3}, ls[4] = {l0, l1, l2, l3};
            float ee[4] = {e0, e1, e2, e3};
            float ksum = 0.f;
#pragma unroll
            for (int k = 0; k < 4; ++k) {
                float var = __expf(2.f * ls[k]);
                float d2 = (mu[k] - ee[k]) * (mu[k] - ee[k]);
                ksum += (-ls[k] + 0.5f * (var + d2) - 0.5f)
                      + ( ls[k] + (1.f + d2) / (2.f * var) - 0.5f);
            }
            accJ += 0.5f * ksum;
        }
    }
    float vC = waveReduceSum(accC), vR = waveReduceSum(accR);
    float vT = waveReduceSum(accT), vJ = waveReduceSum(accJ);
    float vF = waveReduceSum(accF);
    __shared__ float sb[4][5];
    int wid = threadIdx.x >> 6, lid = threadIdx.x & 63;
    if (lid == 0) { sb[wid][0]=vC; sb[wid][1]=vR; sb[wid][2]=vT; sb[wid][3]=vJ; sb[wid][4]=vF; }
    __syncthreads();
    if (threadIdx.x == 0) {
        double C=0,R=0,T=0,J=0,F=0;
        for (int w = 0; w < 4; ++w) { C+=sb[w][0]; R+=sb[w][1]; T+=sb[w][2]; J+=sb[w][3]; F+=sb[w][4]; }
        double* p = part + (size_t)blockIdx.x * 5;
        p[0]=C; p[1]=R; p[2]=T; p[3]=J; p[4]=F;
    }

    // ---- last-block-done final reduction (replaces k_final dispatch) ----
    __shared__ int lastFlag;
    __threadfence();                         // release: publish part slot
    if (threadIdx.x == 0)
        lastFlag = (atomicAdd(cnt, 1u) == (unsigned)(NBF - 1));
    __syncthreads();
    if (!lastFlag) return;
    __threadfence();                         // acquire: see all part slots

    // body identical (same summation order) to the former k_final
    double C = 0, R = 0, T = 0, J = 0, F = 0;
    for (int i = threadIdx.x; i < NBF; i += 256) {
        const double* p = part + (size_t)i * 5;
        C += p[0]; R += p[1]; T += p[2]; J += p[3]; F += p[4];
    }
    for (int o = 32; o > 0; o >>= 1) {
        C += __shfl_down(C, o, 64); R += __shfl_down(R, o, 64);
        T += __shfl_down(T, o, 64); J += __shfl_down(J, o, 64);
        F += __shfl_down(F, o, 64);
    }
    __shared__ double sb2[5][4];
    if (lid == 0) { sb2[0][wid]=C; sb2[1][wid]=R; sb2[2][wid]=T; sb2[3][wid]=J; sb2[4][wid]=F; }
    __syncthreads();
    if (threadIdx.x == 0) {
        double c = sb2[0][0]+sb2[0][1]+sb2[0][2]+sb2[0][3];
        double r = sb2[1][0]+sb2[1][1]+sb2[1][2]+sb2[1][3];
        double t = sb2[2][0]+sb2[2][1]+sb2[2][2]+sb2[2][3];
        double j = sb2[3][0]+sb2[3][1]+sb2[3][2]+sb2[3][3];
        double f = sb2[4][0]+sb2[4][1]+sb2[4][2]+sb2[4][3];
        double ln = 0.9 * 100.0 + 0.1 * fmax(f, 1.0);
        out[0] = (float)(c / ln);
        out[1] = (float)(r / ln);
        out[2] = (float)(t / ln);
        out[3] = (float)(0.1 * j / ln);   // JS_W applied here
    }
}

extern "C" void kernel_launch(void* const* d_in, const int* in_sizes, int n_in,
                              void* d_out, int out_size, void* d_ws, size_t ws_size,
                              hipStream_t stream) {
    (void)in_sizes; (void)n_in; (void)out_size; (void)ws_size;
    const float* pred_cls = (const float*)d_in[0];
    const float* pred_reg = (const float*)d_in[1];
    const float* pred_ctn = (const float*)d_in[2];
    const float* anchors  = (const float*)d_in[3];
    const float* gtb      = (const float*)d_in[4];
    // im_info (d_in[5]) unused

    // ws layout: keys[NROWS] u64 | cnt (8 B, zeroed) | part[NBF*5] doubles
    unsigned long long* keys = (unsigned long long*)d_ws;
    unsigned int* cnt = (unsigned int*)((char*)d_ws + (size_t)NROWS * 8);
    double* part = (double*)((char*)d_ws + (size_t)NROWS * 8 + 8);

    hipMemsetAsync(keys, 0, (size_t)NROWS * 8 + 8, stream);  // keys + counter
    k_assign<<<B_ * M_, 64, 0, stream>>>(anchors, gtb, keys);
    k_fused <<<NBF, 256, 0, stream>>>((const float4*)pred_cls, pred_reg, pred_ctn,
                                      anchors, gtb, keys, part, cnt, (float*)d_out);
}

// Round 3
// 195.059 us; speedup vs baseline: 2.5642x; 1.9930x over previous
//
#include <hip/hip_runtime.h>
#include <math.h>

#define B_      16
#define M_      32
#define A_TOT   21824
#define NROWS   (B_*A_TOT)      // 349184
#define NUM_FG_ 80
#define EPSF    1e-6f
#define NCAND   45
#define NBF     2048            // fused-kernel grid (8 blocks/CU)

__device__ __forceinline__ float waveReduceSum(float v) {
    for (int o = 32; o > 0; o >>= 1) v += __shfl_down(v, o, 64);
    return v;
}

// ---------------- ATSS assignment: one wave per (b, gt) ----------------
// Top-9 nearest per level via analytic 7x7 window (worst-case 9th nearest
// <= 2.13*s, outside-window >= 3.5*s -> no ambiguity; validated absmax==0).
// Extraction by rank-counting in LDS; rank<9 scatters anchor index to
// cand[level*9+rank] -- identical order to the validated wave-min kernel,
// so the threshold tail below is bit-identical.
__global__ __launch_bounds__(64) void k_assign(
    const float* __restrict__ anchors,
    const float* __restrict__ gtb,
    unsigned long long* __restrict__ keys)
{
    const int   lvl_base[5] = {0, 16384, 20480, 21504, 21760};
    const int   lvl_f[5]    = {128, 64, 32, 16, 8};
    const float lvl_s[5]    = {8.f, 16.f, 32.f, 64.f, 128.f};
    int bg = blockIdx.x;
    int b = bg >> 5, g = bg & 31;
    const float* gt = gtb + (b * M_ + g) * 5;
    float g0 = gt[0], g1 = gt[1], g2 = gt[2], g3 = gt[3];
    bool valid = gt[4] > 0.f;
    float gcx = (g0 + g2) * 0.5f, gcy = (g1 + g3) * 0.5f;
    int lane = threadIdx.x;

    __shared__ unsigned long long kbuf[5 * 49];
    __shared__ int cand[NCAND];

    unsigned long long mykey[4];
    int myanchor[4];
    // phase 1: compute 245 candidate keys (centers analytic & exact in fp32)
#pragma unroll
    for (int q = 0; q < 4; ++q) {
        int cid = lane + 64 * q;
        mykey[q] = ~0ULL;
        if (cid < 245) {
            int l = cid / 49, j = cid - l * 49;
            int f = lvl_f[l];
            float s = lvl_s[l];
            int ixn = (int)floorf(gcx / s); ixn = min(max(ixn, 0), f - 1);
            int iyn = (int)floorf(gcy / s); iyn = min(max(iyn, 0), f - 1);
            int ix0 = min(max(ixn - 3, 0), f - 7);
            int iy0 = min(max(iyn - 3, 0), f - 7);
            int ix = ix0 + j % 7, iy = iy0 + j / 7;
            int a = lvl_base[l] + iy * f + ix;   // row=y (ij meshgrid), col=x
            float acx = ((float)ix + 0.5f) * s;  // == (an.x+an.z)*0.5 bit-exact
            float acy = ((float)iy + 0.5f) * s;
            float dx = acx - gcx, dy = acy - gcy;
            float dist = sqrtf(dx * dx + dy * dy);
            mykey[q] = ((unsigned long long)__float_as_uint(dist) << 32) | (unsigned)a;
            myanchor[q] = a;
            kbuf[cid] = mykey[q];
        }
    }
    __syncthreads();
    // phase 2: rank within level; rank<9 -> scatter anchor idx in rank order
#pragma unroll
    for (int q = 0; q < 4; ++q) {
        int cid = lane + 64 * q;
        if (cid < 245) {
            int l = cid / 49;
            const unsigned long long* kg = &kbuf[l * 49];
            int cnt = 0;
            for (int j = 0; j < 49; ++j) cnt += (kg[j] < mykey[q]);
            if (cnt < 9) cand[l * 9 + cnt] = myanchor[q];
        }
    }
    __syncthreads();

    // threshold tail: identical to the validated kernel
    float iou = 0.f; bool inside = false; int a = 0;
    if (lane < NCAND) {
        a = cand[lane];
        float4 an = ((const float4*)anchors)[a];
        float tlx = fmaxf(an.x, g0), tly = fmaxf(an.y, g1);
        float brx = fminf(an.z, g2), bry = fminf(an.w, g3);
        float w = fmaxf(brx - tlx, 0.f), h = fmaxf(bry - tly, 0.f);
        float inter = w * h;
        float aa = (an.z - an.x) * (an.w - an.y);
        float ag = (g2 - g0) * (g3 - g1);
        iou = inter / fmaxf(aa + ag - inter, EPSF);
        float ccx = (an.x + an.z) * 0.5f, ccy = (an.y + an.w) * 0.5f;
        float li = ccx - g0, ti = ccy - g1, ri = g2 - ccx, bi = g3 - ccy;
        inside = fminf(fminf(li, ri), fminf(ti, bi)) > 0.01f;
    }
    float s = waveReduceSum(lane < NCAND ? iou : 0.f);
    float mean = __shfl(s, 0, 64) * (1.f / 45.f);
    float d = (lane < NCAND) ? (iou - mean) : 0.f;
    float ss = waveReduceSum(d * d);
    float thr = mean + sqrtf(__shfl(ss, 0, 64) * (1.f / 44.f));
    if (lane < NCAND && valid && inside && iou >= thr) {
        unsigned long long key =
            ((unsigned long long)__float_as_uint(iou) << 32) | (unsigned)(31 - g);
        atomicMax(&keys[(size_t)b * A_TOT + a], key);
    }
}

// ------- fused: focal cls sweep + fg-row losses (reg/ctn/jsd/fgcount) -------
__global__ __launch_bounds__(256) void k_fused(
    const float4* __restrict__ cls4,
    const float* __restrict__ pred_reg,
    const float* __restrict__ pred_ctn,
    const float* __restrict__ anchors,
    const float* __restrict__ gtb,
    const unsigned long long* __restrict__ keys,
    double* __restrict__ part)
{
    const int total4 = NROWS * (NUM_FG_ / 4);   // 6,983,680; 80%4==0 -> no row-crossing
    float accC = 0.f, accR = 0.f, accT = 0.f, accJ = 0.f, accF = 0.f;
    // unroll 2: two independent float4+keys loads in flight per body;
    // per-thread i-sequence and accumulation order unchanged -> bit-exact.
#pragma unroll 2
    for (int i = blockIdx.x * 256 + threadIdx.x; i < total4; i += NBF * 256) {
        float4 v = cls4[i];                     // plain load: L2/L3-served stream
        int row = i / 20;
        int c0 = (i - row * 20) * 4;
        unsigned long long key = keys[row];
        int tgt = -1;
        int b = row / A_TOT;
        int g = 0;
        if (key) {
            g = 31 - (int)(key & 0xffffffffu);
            tgt = (int)gtb[(b * M_ + g) * 5 + 4] - 1;
        }
        float xs[4] = {v.x, v.y, v.z, v.w};
#pragma unroll
        for (int j = 0; j < 4; ++j) {
            float x = xs[j];
            float p = 1.f / (1.f + __expf(-x));
            float loss;
            if (c0 + j == tgt)
                loss = -0.25f * (1.f - p) * (1.f - p) * __logf(fmaxf(p, 1e-12f));
            else
                loss = -0.75f * p * p * __logf(fmaxf(1.f - p, 1e-12f));
            accC += loss;
        }
        if (c0 == 0 && key) {   // fg-row losses, once per row (rare: ~0.6% of rows)
            accF += 1.f;
            int aidx = row - b * A_TOT;
            const float* gt = gtb + (b * M_ + g) * 5;
            float g0 = gt[0], g1 = gt[1], g2 = gt[2], g3 = gt[3];
            float4 an = ((const float4*)anchors)[aidx];
            float aw = an.z - an.x, ah = an.w - an.y;
            float ax = (an.x + an.z) * 0.5f, ay = (an.y + an.w) * 0.5f;
            float gw = fmaxf(g2 - g0, EPSF), gh = fmaxf(g3 - g1, EPSF);
            float gx = (g0 + g2) * 0.5f, gy = (g1 + g3) * 0.5f;
            float e0 = (gx - ax) / aw, e1 = (gy - ay) / ah;
            float e2 = __logf(gw / aw), e3 = __logf(gh / ah);
            float tw = __expf(fminf(fmaxf(e2, -4.f), 4.f)) * aw;
            float th = __expf(fminf(fmaxf(e3, -4.f), 4.f)) * ah;
            float tcx = ax + e0 * aw, tcy = ay + e1 * ah;
            float tb0 = tcx - 0.5f * tw, tb1 = tcy - 0.5f * th;
            float tb2 = tcx + 0.5f * tw, tb3 = tcy + 0.5f * th;
            const float* pr = pred_reg + (size_t)row * 8;
            float p0 = pr[0], p1 = pr[1], p2 = pr[2], p3 = pr[3];
            float l0 = pr[4], l1 = pr[5], l2 = pr[6], l3 = pr[7];
            float pw = __expf(fminf(fmaxf(p2, -4.f), 4.f)) * aw;
            float ph = __expf(fminf(fmaxf(p3, -4.f), 4.f)) * ah;
            float pcx = ax + p0 * aw, pcy = ay + p1 * ah;
            float pb0 = pcx - 0.5f * pw, pb1 = pcy - 0.5f * ph;
            float pb2 = pcx + 0.5f * pw, pb3 = pcy + 0.5f * ph;
            float tlx = fmaxf(pb0, tb0), tly = fmaxf(pb1, tb1);
            float brx = fminf(pb2, tb2), bry = fminf(pb3, tb3);
            float iw = fmaxf(brx - tlx, 0.f), ih = fmaxf(bry - tly, 0.f);
            float inter = iw * ih;
            float a1 = (pb2 - pb0) * (pb3 - pb1);
            float a2 = (tb2 - tb0) * (tb3 - tb1);
            float uni = fmaxf(a1 + a2 - inter, EPSF);
            float iou = inter / uni;
            float ex0 = fminf(pb0, tb0), ey0 = fminf(pb1, tb1);
            float ex1 = fmaxf(pb2, tb2), ey1 = fmaxf(pb3, tb3);
            float ew = fmaxf(ex1 - ex0, 0.f), eh = fmaxf(ey1 - ey0, 0.f);
            float enc = fmaxf(ew * eh, EPSF);
            accR += 1.f - (iou - (enc - uni) / enc);
            float cl = fmaxf(ax - tb0, EPSF), cr = fmaxf(tb2 - ax, EPSF);
            float ct = fmaxf(ay - tb1, EPSF), cb = fmaxf(tb3 - ay, EPSF);
            float ratio = fminf(cl, cr) / fmaxf(cl, cr) * (fminf(ct, cb) / fmaxf(ct, cb));
            float cstar = sqrtf(fminf(fmaxf(ratio, EPSF), 1.f));
            float z = pred_ctn[row];
            accT += fmaxf(z, 0.f) - z * cstar + log1pf(__expf(-fabsf(z)));
            float mu[4] = {p0, p1, p2, p3}, ls[4] = {l0, l1, l2, l3};
            float ee[4] = {e0, e1, e2, e3};
            float ksum = 0.f;
#pragma unroll
            for (int k = 0; k < 4; ++k) {
                float var = __expf(2.f * ls[k]);
                float d2 = (mu[k] - ee[k]) * (mu[k] - ee[k]);
                ksum += (-ls[k] + 0.5f * (var + d2) - 0.5f)
                      + ( ls[k] + (1.f + d2) / (2.f * var) - 0.5f);
            }
            accJ += 0.5f * ksum;
        }
    }
    float vC = waveReduceSum(accC), vR = waveReduceSum(accR);
    float vT = waveReduceSum(accT), vJ = waveReduceSum(accJ);
    float vF = waveReduceSum(accF);
    __shared__ float sb[4][5];
    int wid = threadIdx.x >> 6, lid = threadIdx.x & 63;
    if (lid == 0) { sb[wid][0]=vC; sb[wid][1]=vR; sb[wid][2]=vT; sb[wid][3]=vJ; sb[wid][4]=vF; }
    __syncthreads();
    if (threadIdx.x == 0) {
        double C=0,R=0,T=0,J=0,F=0;
        for (int w = 0; w < 4; ++w) { C+=sb[w][0]; R+=sb[w][1]; T+=sb[w][2]; J+=sb[w][3]; F+=sb[w][4]; }
        double* p = part + (size_t)blockIdx.x * 5;
        p[0]=C; p[1]=R; p[2]=T; p[3]=J; p[4]=F;
    }
}

// ---------------- final reduction + normalization ----------------
// Kept as a separate dispatch ON PURPOSE: fusing via threadfence+atomic
// (R1/R2) cost ~215us — 2048 concurrent agent-scope fences each emit an
// L2 writeback (buffer_wbl2) on non-coherent-XCD gfx950 and the storm
// serializes at the 8 L2s. A kernel boundary is the cheap device release.
__global__ __launch_bounds__(256) void k_final(
    const double* __restrict__ part,
    float* __restrict__ out)
{
    double C = 0, R = 0, T = 0, J = 0, F = 0;
    for (int i = threadIdx.x; i < NBF; i += 256) {
        const double* p = part + (size_t)i * 5;
        C += p[0]; R += p[1]; T += p[2]; J += p[3]; F += p[4];
    }
    for (int o = 32; o > 0; o >>= 1) {
        C += __shfl_down(C, o, 64); R += __shfl_down(R, o, 64);
        T += __shfl_down(T, o, 64); J += __shfl_down(J, o, 64);
        F += __shfl_down(F, o, 64);
    }
    __shared__ double sb[5][4];
    int wid = threadIdx.x >> 6, lid = threadIdx.x & 63;
    if (lid == 0) { sb[0][wid]=C; sb[1][wid]=R; sb[2][wid]=T; sb[3][wid]=J; sb[4][wid]=F; }
    __syncthreads();
    if (threadIdx.x == 0) {
        double c = sb[0][0]+sb[0][1]+sb[0][2]+sb[0][3];
        double r = sb[1][0]+sb[1][1]+sb[1][2]+sb[1][3];
        double t = sb[2][0]+sb[2][1]+sb[2][2]+sb[2][3];
        double j = sb[3][0]+sb[3][1]+sb[3][2]+sb[3][3];
        double f = sb[4][0]+sb[4][1]+sb[4][2]+sb[4][3];
        double ln = 0.9 * 100.0 + 0.1 * fmax(f, 1.0);
        out[0] = (float)(c / ln);
        out[1] = (float)(r / ln);
        out[2] = (float)(t / ln);
        out[3] = (float)(0.1 * j / ln);   // JS_W applied here
    }
}

extern "C" void kernel_launch(void* const* d_in, const int* in_sizes, int n_in,
                              void* d_out, int out_size, void* d_ws, size_t ws_size,
                              hipStream_t stream) {
    (void)in_sizes; (void)n_in; (void)out_size; (void)ws_size;
    const float* pred_cls = (const float*)d_in[0];
    const float* pred_reg = (const float*)d_in[1];
    const float* pred_ctn = (const float*)d_in[2];
    const float* anchors  = (const float*)d_in[3];
    const float* gtb      = (const float*)d_in[4];
    // im_info (d_in[5]) unused

    unsigned long long* keys = (unsigned long long*)d_ws;          // NROWS * 8 B
    double* part = (double*)((char*)d_ws + (size_t)NROWS * 8);     // NBF * 5 doubles

    hipMemsetAsync(keys, 0, (size_t)NROWS * 8, stream);            // zero best-key table
    k_assign<<<B_ * M_, 64, 0, stream>>>(anchors, gtb, keys);
    k_fused <<<NBF, 256, 0, stream>>>((const float4*)pred_cls, pred_reg, pred_ctn,
                                      anchors, gtb, keys, part);
    k_final <<<1, 256, 0, stream>>>(part, (float*)d_out);
}

// Round 4
// 189.650 us; speedup vs baseline: 2.6373x; 1.0285x over previous
//
#include <hip/hip_runtime.h>
#include <math.h>

#define B_      16
#define M_      32
#define A_TOT   21824
#define NROWS   (B_*A_TOT)      // 349184
#define NUM_FG_ 80
#define EPSF    1e-6f
#define NCAND   45
#define NBF     2048            // fused-kernel grid (8 blocks/CU)

__device__ __forceinline__ float waveReduceSum(float v) {
    for (int o = 32; o > 0; o >>= 1) v += __shfl_down(v, o, 64);
    return v;
}

// ---------------- ATSS assignment: one wave per (b, gt) ----------------
// Top-9 nearest per level via analytic 7x7 window (worst-case 9th nearest
// <= 2.13*s, outside-window >= 3.5*s -> no ambiguity; validated absmax==0).
// Extraction by rank-counting in LDS; rank<9 scatters anchor index to
// cand[level*9+rank] -- identical order to the validated wave-min kernel,
// so the threshold tail below is bit-identical.
__global__ __launch_bounds__(64) void k_assign(
    const float* __restrict__ anchors,
    const float* __restrict__ gtb,
    unsigned long long* __restrict__ keys)
{
    const int   lvl_base[5] = {0, 16384, 20480, 21504, 21760};
    const int   lvl_f[5]    = {128, 64, 32, 16, 8};
    const float lvl_s[5]    = {8.f, 16.f, 32.f, 64.f, 128.f};
    int bg = blockIdx.x;
    int b = bg >> 5, g = bg & 31;
    const float* gt = gtb + (b * M_ + g) * 5;
    float g0 = gt[0], g1 = gt[1], g2 = gt[2], g3 = gt[3];
    bool valid = gt[4] > 0.f;
    float gcx = (g0 + g2) * 0.5f, gcy = (g1 + g3) * 0.5f;
    int lane = threadIdx.x;

    __shared__ unsigned long long kbuf[5 * 49];
    __shared__ int cand[NCAND];

    unsigned long long mykey[4];
    int myanchor[4];
    // phase 1: compute 245 candidate keys (centers analytic & exact in fp32)
#pragma unroll
    for (int q = 0; q < 4; ++q) {
        int cid = lane + 64 * q;
        mykey[q] = ~0ULL;
        if (cid < 245) {
            int l = cid / 49, j = cid - l * 49;
            int f = lvl_f[l];
            float s = lvl_s[l];
            int ixn = (int)floorf(gcx / s); ixn = min(max(ixn, 0), f - 1);
            int iyn = (int)floorf(gcy / s); iyn = min(max(iyn, 0), f - 1);
            int ix0 = min(max(ixn - 3, 0), f - 7);
            int iy0 = min(max(iyn - 3, 0), f - 7);
            int ix = ix0 + j % 7, iy = iy0 + j / 7;
            int a = lvl_base[l] + iy * f + ix;   // row=y (ij meshgrid), col=x
            float acx = ((float)ix + 0.5f) * s;  // == (an.x+an.z)*0.5 bit-exact
            float acy = ((float)iy + 0.5f) * s;
            float dx = acx - gcx, dy = acy - gcy;
            float dist = sqrtf(dx * dx + dy * dy);
            mykey[q] = ((unsigned long long)__float_as_uint(dist) << 32) | (unsigned)a;
            myanchor[q] = a;
            kbuf[cid] = mykey[q];
        }
    }
    __syncthreads();
    // phase 2: rank within level; rank<9 -> scatter anchor idx in rank order
#pragma unroll
    for (int q = 0; q < 4; ++q) {
        int cid = lane + 64 * q;
        if (cid < 245) {
            int l = cid / 49;
            const unsigned long long* kg = &kbuf[l * 49];
            int cnt = 0;
            for (int j = 0; j < 49; ++j) cnt += (kg[j] < mykey[q]);
            if (cnt < 9) cand[l * 9 + cnt] = myanchor[q];
        }
    }
    __syncthreads();

    // threshold tail: identical to the validated kernel
    float iou = 0.f; bool inside = false; int a = 0;
    if (lane < NCAND) {
        a = cand[lane];
        float4 an = ((const float4*)anchors)[a];
        float tlx = fmaxf(an.x, g0), tly = fmaxf(an.y, g1);
        float brx = fminf(an.z, g2), bry = fminf(an.w, g3);
        float w = fmaxf(brx - tlx, 0.f), h = fmaxf(bry - tly, 0.f);
        float inter = w * h;
        float aa = (an.z - an.x) * (an.w - an.y);
        float ag = (g2 - g0) * (g3 - g1);
        iou = inter / fmaxf(aa + ag - inter, EPSF);
        float ccx = (an.x + an.z) * 0.5f, ccy = (an.y + an.w) * 0.5f;
        float li = ccx - g0, ti = ccy - g1, ri = g2 - ccx, bi = g3 - ccy;
        inside = fminf(fminf(li, ri), fminf(ti, bi)) > 0.01f;
    }
    float s = waveReduceSum(lane < NCAND ? iou : 0.f);
    float mean = __shfl(s, 0, 64) * (1.f / 45.f);
    float d = (lane < NCAND) ? (iou - mean) : 0.f;
    float ss = waveReduceSum(d * d);
    float thr = mean + sqrtf(__shfl(ss, 0, 64) * (1.f / 44.f));
    if (lane < NCAND && valid && inside && iou >= thr) {
        unsigned long long key =
            ((unsigned long long)__float_as_uint(iou) << 32) | (unsigned)(31 - g);
        atomicMax(&keys[(size_t)b * A_TOT + a], key);
    }
}

// ------- fused: focal cls sweep + fg-row losses (reg/ctn/jsd/fgcount) -------
// NOTE (session journal, do not re-try):
//  - __builtin_nontemporal_load on the cls stream: -75us (R1). The stream is
//    L2/L3-resident across iterations; nt bypasses the caches serving it.
//  - in-kernel final reduction via __threadfence + atomic counter: -215us
//    (R1/R2). 2048 concurrent device-scope release fences each trigger an
//    L2 writeback on non-coherent-XCD gfx950; the storm serializes at the
//    8 per-XCD L2s. A kernel boundary is the cheap device-wide release.
//  - #pragma unroll 2 on the grid-stride loop: ~-5us (R3). At ~20 waves/CU
//    occupancy TLP already hides load latency; ILP-unroll is null-to-negative
//    on this memory-bound streaming loop.
__global__ __launch_bounds__(256) void k_fused(
    const float4* __restrict__ cls4,
    const float* __restrict__ pred_reg,
    const float* __restrict__ pred_ctn,
    const float* __restrict__ anchors,
    const float* __restrict__ gtb,
    const unsigned long long* __restrict__ keys,
    double* __restrict__ part)
{
    const int total4 = NROWS * (NUM_FG_ / 4);   // 6,983,680; 80%4==0 -> no row-crossing
    float accC = 0.f, accR = 0.f, accT = 0.f, accJ = 0.f, accF = 0.f;
    for (int i = blockIdx.x * 256 + threadIdx.x; i < total4; i += NBF * 256) {
        float4 v = cls4[i];
        int row = i / 20;
        int c0 = (i - row * 20) * 4;
        unsigned long long key = keys[row];
        int tgt = -1;
        int b = row / A_TOT;
        int g = 0;
        if (key) {
            g = 31 - (int)(key & 0xffffffffu);
            tgt = (int)gtb[(b * M_ + g) * 5 + 4] - 1;
        }
        float xs[4] = {v.x, v.y, v.z, v.w};
#pragma unroll
        for (int j = 0; j < 4; ++j) {
            float x = xs[j];
            float p = 1.f / (1.f + __expf(-x));
            float loss;
            if (c0 + j == tgt)
                loss = -0.25f * (1.f - p) * (1.f - p) * __logf(fmaxf(p, 1e-12f));
            else
                loss = -0.75f * p * p * __logf(fmaxf(1.f - p, 1e-12f));
            accC += loss;
        }
        if (c0 == 0 && key) {   // fg-row losses, once per row (rare: ~0.6% of rows)
            accF += 1.f;
            int aidx = row - b * A_TOT;
            const float* gt = gtb + (b * M_ + g) * 5;
            float g0 = gt[0], g1 = gt[1], g2 = gt[2], g3 = gt[3];
            float4 an = ((const float4*)anchors)[aidx];
            float aw = an.z - an.x, ah = an.w - an.y;
            float ax = (an.x + an.z) * 0.5f, ay = (an.y + an.w) * 0.5f;
            float gw = fmaxf(g2 - g0, EPSF), gh = fmaxf(g3 - g1, EPSF);
            float gx = (g0 + g2) * 0.5f, gy = (g1 + g3) * 0.5f;
            float e0 = (gx - ax) / aw, e1 = (gy - ay) / ah;
            float e2 = __logf(gw / aw), e3 = __logf(gh / ah);
            float tw = __expf(fminf(fmaxf(e2, -4.f), 4.f)) * aw;
            float th = __expf(fminf(fmaxf(e3, -4.f), 4.f)) * ah;
            float tcx = ax + e0 * aw, tcy = ay + e1 * ah;
            float tb0 = tcx - 0.5f * tw, tb1 = tcy - 0.5f * th;
            float tb2 = tcx + 0.5f * tw, tb3 = tcy + 0.5f * th;
            const float* pr = pred_reg + (size_t)row * 8;
            float p0 = pr[0], p1 = pr[1], p2 = pr[2], p3 = pr[3];
            float l0 = pr[4], l1 = pr[5], l2 = pr[6], l3 = pr[7];
            float pw = __expf(fminf(fmaxf(p2, -4.f), 4.f)) * aw;
            float ph = __expf(fminf(fmaxf(p3, -4.f), 4.f)) * ah;
            float pcx = ax + p0 * aw, pcy = ay + p1 * ah;
            float pb0 = pcx - 0.5f * pw, pb1 = pcy - 0.5f * ph;
            float pb2 = pcx + 0.5f * pw, pb3 = pcy + 0.5f * ph;
            float tlx = fmaxf(pb0, tb0), tly = fmaxf(pb1, tb1);
            float brx = fminf(pb2, tb2), bry = fminf(pb3, tb3);
            float iw = fmaxf(brx - tlx, 0.f), ih = fmaxf(bry - tly, 0.f);
            float inter = iw * ih;
            float a1 = (pb2 - pb0) * (pb3 - pb1);
            float a2 = (tb2 - tb0) * (tb3 - tb1);
            float uni = fmaxf(a1 + a2 - inter, EPSF);
            float iou = inter / uni;
            float ex0 = fminf(pb0, tb0), ey0 = fminf(pb1, tb1);
            float ex1 = fmaxf(pb2, tb2), ey1 = fmaxf(pb3, tb3);
            float ew = fmaxf(ex1 - ex0, 0.f), eh = fmaxf(ey1 - ey0, 0.f);
            float enc = fmaxf(ew * eh, EPSF);
            accR += 1.f - (iou - (enc - uni) / enc);
            float cl = fmaxf(ax - tb0, EPSF), cr = fmaxf(tb2 - ax, EPSF);
            float ct = fmaxf(ay - tb1, EPSF), cb = fmaxf(tb3 - ay, EPSF);
            float ratio = fminf(cl, cr) / fmaxf(cl, cr) * (fminf(ct, cb) / fmaxf(ct, cb));
            float cstar = sqrtf(fminf(fmaxf(ratio, EPSF), 1.f));
            float z = pred_ctn[row];
            accT += fmaxf(z, 0.f) - z * cstar + log1pf(__expf(-fabsf(z)));
            float mu[4] = {p0, p1, p2, p3}, ls[4] = {l0, l1, l2, l3};
            float ee[4] = {e0, e1, e2, e3};
            float ksum = 0.f;
#pragma unroll
            for (int k = 0; k < 4; ++k) {
                float var = __expf(2.f * ls[k]);
                float d2 = (mu[k] - ee[k]) * (mu[k] - ee[k]);
                ksum += (-ls[k] + 0.5f * (var + d2) - 0.5f)
                      + ( ls[k] + (1.f + d2) / (2.f * var) - 0.5f);
            }
            accJ += 0.5f * ksum;
        }
    }
    float vC = waveReduceSum(accC), vR = waveReduceSum(accR);
    float vT = waveReduceSum(accT), vJ = waveReduceSum(accJ);
    float vF = waveReduceSum(accF);
    __shared__ float sb[4][5];
    int wid = threadIdx.x >> 6, lid = threadIdx.x & 63;
    if (lid == 0) { sb[wid][0]=vC; sb[wid][1]=vR; sb[wid][2]=vT; sb[wid][3]=vJ; sb[wid][4]=vF; }
    __syncthreads();
    if (threadIdx.x == 0) {
        double C=0,R=0,T=0,J=0,F=0;
        for (int w = 0; w < 4; ++w) { C+=sb[w][0]; R+=sb[w][1]; T+=sb[w][2]; J+=sb[w][3]; F+=sb[w][4]; }
        double* p = part + (size_t)blockIdx.x * 5;
        p[0]=C; p[1]=R; p[2]=T; p[3]=J; p[4]=F;
    }
}

// ---------------- final reduction + normalization ----------------
// Kept as a separate dispatch ON PURPOSE (see journal note above k_fused).
__global__ __launch_bounds__(256) void k_final(
    const double* __restrict__ part,
    float* __restrict__ out)
{
    double C = 0, R = 0, T = 0, J = 0, F = 0;
    for (int i = threadIdx.x; i < NBF; i += 256) {
        const double* p = part + (size_t)i * 5;
        C += p[0]; R += p[1]; T += p[2]; J += p[3]; F += p[4];
    }
    for (int o = 32; o > 0; o >>= 1) {
        C += __shfl_down(C, o, 64); R += __shfl_down(R, o, 64);
        T += __shfl_down(T, o, 64); J += __shfl_down(J, o, 64);
        F += __shfl_down(F, o, 64);
    }
    __shared__ double sb[5][4];
    int wid = threadIdx.x >> 6, lid = threadIdx.x & 63;
    if (lid == 0) { sb[0][wid]=C; sb[1][wid]=R; sb[2][wid]=T; sb[3][wid]=J; sb[4][wid]=F; }
    __syncthreads();
    if (threadIdx.x == 0) {
        double c = sb[0][0]+sb[0][1]+sb[0][2]+sb[0][3];
        double r = sb[1][0]+sb[1][1]+sb[1][2]+sb[1][3];
        double t = sb[2][0]+sb[2][1]+sb[2][2]+sb[2][3];
        double j = sb[3][0]+sb[3][1]+sb[3][2]+sb[3][3];
        double f = sb[4][0]+sb[4][1]+sb[4][2]+sb[4][3];
        double ln = 0.9 * 100.0 + 0.1 * fmax(f, 1.0);
        out[0] = (float)(c / ln);
        out[1] = (float)(r / ln);
        out[2] = (float)(t / ln);
        out[3] = (float)(0.1 * j / ln);   // JS_W applied here
    }
}

extern "C" void kernel_launch(void* const* d_in, const int* in_sizes, int n_in,
                              void* d_out, int out_size, void* d_ws, size_t ws_size,
                              hipStream_t stream) {
    (void)in_sizes; (void)n_in; (void)out_size; (void)ws_size;
    const float* pred_cls = (const float*)d_in[0];
    const float* pred_reg = (const float*)d_in[1];
    const float* pred_ctn = (const float*)d_in[2];
    const float* anchors  = (const float*)d_in[3];
    const float* gtb      = (const float*)d_in[4];
    // im_info (d_in[5]) unused

    unsigned long long* keys = (unsigned long long*)d_ws;          // NROWS * 8 B
    double* part = (double*)((char*)d_ws + (size_t)NROWS * 8);     // NBF * 5 doubles

    hipMemsetAsync(keys, 0, (size_t)NROWS * 8, stream);            // zero best-key table
    k_assign<<<B_ * M_, 64, 0, stream>>>(anchors, gtb, keys);
    k_fused <<<NBF, 256, 0, stream>>>((const float4*)pred_cls, pred_reg, pred_ctn,
                                      anchors, gtb, keys, part);
    k_final <<<1, 256, 0, stream>>>(part, (float*)d_out);
}